// Round 10
// baseline (548.683 us; speedup 1.0000x reference)
//
#include <hip/hip_runtime.h>

#define NB 16
#define NN 2048
#define NP 512
#define NS 32
#define NC 64
#define NWORK 240

typedef _Float16 f16x8 __attribute__((ext_vector_type(8)));
typedef _Float16 f16x4 __attribute__((ext_vector_type(4)));
typedef float f32x4 __attribute__((ext_vector_type(4)));
typedef float f32x2 __attribute__((ext_vector_type(2)));

__device__ __forceinline__ float sqdist(float dx, float dy, float dz) {
  return __fadd_rn(__fadd_rn(__fmul_rn(dx, dx), __fmul_rn(dy, dy)), __fmul_rn(dz, dz));
}

__device__ __forceinline__ f32x2 pk_add(f32x2 a, f32x2 b) {
  f32x2 d;
  asm("v_pk_add_f32 %0, %1, %2" : "=v"(d) : "v"(a), "v"(b));
  return d;
}
__device__ __forceinline__ f32x2 pk_mul(f32x2 a, f32x2 b) {
  f32x2 d;
  asm("v_pk_mul_f32 %0, %1, %2" : "=v"(d) : "v"(a), "v"(b));
  return d;
}

template <int CTRL>
__device__ __forceinline__ float dppmaxf(float m) {
  int t = __builtin_amdgcn_update_dpp(0, __float_as_int(m), CTRL, 0xf, 0xf, true);
  return fmaxf(m, __int_as_float(t));  // 0-fill safe: all values >= 0
}

__device__ __forceinline__ unsigned ld_relax(const unsigned* p) {
  return __hip_atomic_load(p, __ATOMIC_RELAXED, __HIP_MEMORY_SCOPE_AGENT);
}
__device__ __forceinline__ void waitge(const unsigned* p, unsigned need) {
  if (ld_relax(p) < need) {
    unsigned spins = 0;
    while (ld_relax(p) < need) {
      __builtin_amdgcn_s_sleep(8);
      if (++spins > (1u << 22)) break;  // safety valve — never expected
    }
  }
  (void)__hip_atomic_load(p, __ATOMIC_ACQUIRE, __HIP_MEMORY_SCOPE_AGENT);
}

__global__ void init_kernel(unsigned* ctr) {
  if (threadIdx.x < 18) ctr[threadIdx.x * 16] = 0;  // 64B-strided counters
}

#define HSTR 104   // hT stride in f16 (96 padded)
#define A1STR 72   // a1 stride (64 padded)
#define A2STR 136  // a2 stride (128 padded)
#define A1OFF 17408

// ---------------------------------------------------------------------------
// Fused persistent kernel, 256 blocks (all co-resident; FPS gets dedicated CUs):
//   blocks 0..15   : FPS producer; centroids staged in LDS, published every 32
//                    iters (batched agent-scope stores + release counter).
//                    Per-wave winner carries xyz in the LDS tuple -> no
//                    dependent XL read, no per-iter global-store drain.
//   blocks 16..255 : prep/wconv -> stage gate -> item queue: (b,sg) ball+MFMA
// ---------------------------------------------------------------------------
__global__ __launch_bounds__(256, 2) void fused_kernel(
    const float* __restrict__ xyz, const float* __restrict__ feat,
    const float* __restrict__ W1, const float* __restrict__ b1, const float* __restrict__ W2,
    const float* __restrict__ b2, const float* __restrict__ W3, const float* __restrict__ b3,
    float* __restrict__ out, _Float16* __restrict__ featF, float* __restrict__ xyzT,
    _Float16* __restrict__ W1f, _Float16* __restrict__ W2f, _Float16* __restrict__ W3f,
    unsigned* __restrict__ ctr) {
  __shared__ __align__(16) char sm[53824];
  __shared__ unsigned mitem;
  const int bid = blockIdx.x;
  const int t = threadIdx.x;
  float* newxyz = out;

  if (bid < NB) {
    // ================= FPS producer role =================
    const int b = bid;
    const int w = t >> 6;
    const float* X = xyz + (size_t)b * 3 * NN;
    float* cst = (float*)sm;                      // 3*512*4 = 6144 B
    unsigned* ck = (unsigned*)(sm + 6144);        // [2][4][8] u32 = 256 B

    f32x2 px[4], py[4], pz[4], dist[4];
#pragma unroll
    for (int jj = 0; jj < 4; ++jj) {
      int n0 = t + 256 * jj, n1 = n0 + 1024;
      px[jj] = f32x2{X[n0], X[n1]};
      py[jj] = f32x2{X[NN + n0], X[NN + n1]};
      pz[jj] = f32x2{X[2 * NN + n0], X[2 * NN + n1]};
      dist[jj] = f32x2{1e10f, 1e10f};
    }
    float cx = X[0], cy = X[NN], cz = X[2 * NN];
    int buf = 0;
    for (int i = 0; i < NP; ++i) {
      if (t == 0) {
        cst[i] = cx;
        cst[NP + i] = cy;
        cst[2 * NP + i] = cz;
      }
      const f32x2 ncx = f32x2{-cx, -cx}, ncy = f32x2{-cy, -cy}, ncz = f32x2{-cz, -cz};
      float hm[4];
#pragma unroll
      for (int jj = 0; jj < 4; ++jj) {
        f32x2 dx = pk_add(px[jj], ncx);
        f32x2 dy = pk_add(py[jj], ncy);
        f32x2 dz = pk_add(pz[jj], ncz);
        f32x2 s = pk_add(pk_add(pk_mul(dx, dx), pk_mul(dy, dy)), pk_mul(dz, dz));
        f32x2 d = dist[jj];
        d.x = fminf(d.x, s.x);
        d.y = fminf(d.y, s.y);
        dist[jj] = d;
        hm[jj] = fmaxf(d.x, d.y);
      }
      // phase A: wave max value
      float m = fmaxf(fmaxf(hm[0], hm[1]), fmaxf(hm[2], hm[3]));
      m = dppmaxf<0x111>(m);
      m = dppmaxf<0x112>(m);
      m = dppmaxf<0x114>(m);
      m = dppmaxf<0x118>(m);
      m = dppmaxf<0x142>(m);
      m = dppmaxf<0x143>(m);
      const float vmax = __int_as_float(__builtin_amdgcn_readlane(__float_as_int(m), 63));
      // phase B: ballots + scalar first-set scan (min n, exact)
      unsigned long long mm[8];
#pragma unroll
      for (int jj = 0; jj < 4; ++jj) {
        mm[jj] = __ballot(dist[jj].x == vmax);
        mm[4 + jj] = __ballot(dist[jj].y == vmax);
      }
      unsigned nw = 0;
#pragma unroll
      for (int q = 7; q >= 0; --q)
        if (mm[q]) nw = 256u * (unsigned)q + (unsigned)(w << 6) + (unsigned)__builtin_ctzll(mm[q]);
      // winner-xyz select (q uniform, compile-time element accesses)
      const unsigned q = nw >> 8;
      float sx = (q == 0)   ? px[0].x
                 : (q == 1) ? px[1].x
                 : (q == 2) ? px[2].x
                 : (q == 3) ? px[3].x
                 : (q == 4) ? px[0].y
                 : (q == 5) ? px[1].y
                 : (q == 6) ? px[2].y
                            : px[3].y;
      float sy = (q == 0)   ? py[0].x
                 : (q == 1) ? py[1].x
                 : (q == 2) ? py[2].x
                 : (q == 3) ? py[3].x
                 : (q == 4) ? py[0].y
                 : (q == 5) ? py[1].y
                 : (q == 6) ? py[2].y
                            : py[3].y;
      float sz = (q == 0)   ? pz[0].x
                 : (q == 1) ? pz[1].x
                 : (q == 2) ? pz[2].x
                 : (q == 3) ? pz[3].x
                 : (q == 4) ? pz[0].y
                 : (q == 5) ? pz[1].y
                 : (q == 6) ? pz[2].y
                            : pz[3].y;
      if (t == (int)(nw & 255u)) {  // owner thread of this wave's candidate
        unsigned* c = ck + buf * 32 + w * 8;
        *(uint4*)c = make_uint4(__float_as_uint(vmax), nw, __float_as_uint(sx),
                                __float_as_uint(sy));
        c[4] = __float_as_uint(sz);
      }
      __syncthreads();
      // cross-wave merge: 4 independent tuple reads, 3 lex compares
      const unsigned* cb = ck + buf * 32;
      uint4 a0 = *(const uint4*)(cb + 0);
      unsigned z0 = cb[4];
      uint4 a1 = *(const uint4*)(cb + 8);
      unsigned z1 = cb[12];
      uint4 a2 = *(const uint4*)(cb + 16);
      unsigned z2 = cb[20];
      uint4 a3 = *(const uint4*)(cb + 24);
      unsigned z3 = cb[28];
      unsigned k = a0.x, n = a0.y, xr = a0.z, yr = a0.w, zr = z0;
      if (a1.x > k || (a1.x == k && a1.y < n)) { k = a1.x; n = a1.y; xr = a1.z; yr = a1.w; zr = z1; }
      if (a2.x > k || (a2.x == k && a2.y < n)) { k = a2.x; n = a2.y; xr = a2.z; yr = a2.w; zr = z2; }
      if (a3.x > k || (a3.x == k && a3.y < n)) { k = a3.x; n = a3.y; xr = a3.z; yr = a3.w; zr = z3; }
      cx = __uint_as_float(xr);
      cy = __uint_as_float(yr);
      cz = __uint_as_float(zr);
      // batched publish every 32 iterations (off critical path, amortized)
      if ((i & 31) == 31) {
        if (t < 96) {
          int coord = t >> 5, j = (i - 31) + (t & 31);
          __hip_atomic_store(&newxyz[b * 3 * NP + coord * NP + j], cst[coord * NP + j],
                             __ATOMIC_RELAXED, __HIP_MEMORY_SCOPE_AGENT);
        }
        __syncthreads();  // all dump stores drained (vmcnt) before release
        if (t == 0)
          __hip_atomic_store(&ctr[b * 16], (unsigned)(i + 1), __ATOMIC_RELEASE,
                             __HIP_MEMORY_SCOPE_AGENT);
      }
      buf ^= 1;
    }
  } else {
    // ================= worker role: prep + wconv, then stage release =======
    const int wid = bid - NB;
    for (int rep = 0; rep < 3; ++rep) {
      int p = wid + rep * NWORK;
      if (p >= 512) break;
      float(*tile)[65] = (float(*)[65])sm;
      const int b = p >> 5;
      const int n0 = (p & 31) * 64;
      const int g = t >> 6, l = t & 63;
      if (g == 0) {
        int n = n0 + l;
        float4 qd;
        qd.x = xyz[(size_t)b * 3 * NN + n];
        qd.y = xyz[(size_t)b * 3 * NN + NN + n];
        qd.z = xyz[(size_t)b * 3 * NN + 2 * NN + n];
        qd.w = 0.f;
        ((float4*)xyzT)[(size_t)b * NN + n] = qd;
      }
      __syncthreads();  // tile reuse across reps
#pragma unroll
      for (int r = 0; r < 16; ++r) {
        int c = g * 16 + r;
        tile[c][l] = feat[((size_t)b * NC + c) * NN + n0 + l];
      }
      __syncthreads();
#pragma unroll
      for (int r = 0; r < 16; ++r) {
        int nl = g * 16 + r;
        featF[((size_t)(b * NN + n0 + nl)) * NC + l] = (_Float16)tile[l][nl];
      }
    }
    if (wid == 31) {
      for (int i = t; i < 256 * 128; i += 256) {
        if (i < 64 * 96) {
          int o = i / 96, k = i - o * 96;
          float v = (k < 64) ? W1[o * 67 + 3 + k] : ((k < 67) ? W1[o * 67 + (k - 64)] : 0.f);
          W1f[i] = (_Float16)v;
        }
        if (i < 128 * 64) W2f[i] = (_Float16)W2[i];
        W3f[i] = (_Float16)W3[i];
      }
    }
    __syncthreads();  // all waves' stores drained before release
    if (t == 0)
      (void)__hip_atomic_fetch_add(&ctr[16 * 16], 1u, __ATOMIC_RELEASE,
                                   __HIP_MEMORY_SCOPE_AGENT);
  }

  // ================= stage gate, then item queue =================
  if (t == 0) waitge(&ctr[16 * 16], NWORK);
  __syncthreads();

  _Float16* hT = (_Float16*)sm;
  _Float16* a1T = (_Float16*)(sm) + A1OFF;
  int(*idx_l)[32] = (int(*)[32])(sm + 53248);
  float(*cxyz)[4] = (float(*)[4])(sm + 53760);
  const int lane = t & 63, w = t >> 6;
  const int cl = lane & 15;
  const int kg = lane >> 4;
  float* out2 = out + NB * 3 * NP;

  for (;;) {
    if (t == 0)
      mitem = __hip_atomic_fetch_add(&ctr[17 * 16], 1u, __ATOMIC_RELAXED,
                                     __HIP_MEMORY_SCOPE_AGENT);
    __syncthreads();
    const unsigned m = mitem;
    if (m >= (unsigned)(NB * 128)) break;
    const int b = (int)(m & 15u);
    const int sg = (int)(m >> 4);
    const int s0 = sg * 4;
    if (t == 0) waitge(&ctr[b * 16], (unsigned)(s0 + 4));
    __syncthreads();

    // ---- phase 0: ball query, one wave per s (bit-exact ballot scan)
    {
      const float* X = xyz + (size_t)b * 3 * NN;
      const int sW = s0 + w;
      const float cxw = newxyz[b * 3 * NP + sW];
      const float cyw = newxyz[b * 3 * NP + NP + sW];
      const float czw = newxyz[b * 3 * NP + 2 * NP + sW];
      if (lane == 0) {
        cxyz[w][0] = cxw;
        cxyz[w][1] = cyw;
        cxyz[w][2] = czw;
      }
      const float r2 = (float)(0.2 * 0.2);
      int total = 0, first = 0;
      bool havefirst = false;
      for (int c0 = 0; c0 < NN; c0 += 64) {
        int n = c0 + lane;
        float d2 = sqdist(X[n] - cxw, X[NN + n] - cyw, X[2 * NN + n] - czw);
        bool hit = d2 < r2;
        unsigned long long mask = __ballot(hit);
        if (!havefirst && mask) {
          first = c0 + __builtin_ctzll(mask);
          havefirst = true;
        }
        if (hit) {
          int pos = total + (int)__popcll(mask & ((1ull << lane) - 1ull));
          if (pos < NS) idx_l[w][pos] = n;
        }
        total += (int)__popcll(mask);
        if (total >= NS) break;
      }
      if (total < NS && lane >= total && lane < NS) idx_l[w][lane] = first;
    }
    __syncthreads();

    // ---- phase 1: gather hT[128 cols][96 k]
    {
      const int col = t & 127, hf = t >> 7;
      const int n = idx_l[col >> 5][col & 31];
      const _Float16* F = featF + (size_t)(b * NN + n) * NC;
#pragma unroll
      for (int j = 0; j < 4; ++j) {
        int p = hf * 4 + j;
        *(f16x8*)(&hT[col * HSTR + p * 8]) = *(const f16x8*)(F + p * 8);
      }
      if (hf == 0) {
        float4 pnt = ((const float4*)xyzT)[(size_t)b * NN + n];
        f16x8 v = {};
        v[0] = (_Float16)(pnt.x - cxyz[col >> 5][0]);
        v[1] = (_Float16)(pnt.y - cxyz[col >> 5][1]);
        v[2] = (_Float16)(pnt.z - cxyz[col >> 5][2]);
        *(f16x8*)(&hT[col * HSTR + 64]) = v;
      } else {
        f16x8 z = {};
        *(f16x8*)(&hT[col * HSTR + 72]) = z;
        *(f16x8*)(&hT[col * HSTR + 80]) = z;
        *(f16x8*)(&hT[col * HSTR + 88]) = z;
      }
    }
    __syncthreads();

    // ---- layer 1: K=96, O=64
    {
      f32x4 acc[8];
      {
        f32x4 bb = *(const f32x4*)(b1 + w * 16 + kg * 4);
#pragma unroll
        for (int ct = 0; ct < 8; ++ct) acc[ct] = bb;
      }
#pragma unroll
      for (int ks = 0; ks < 3; ++ks) {
        f16x8 A = *(const f16x8*)(W1f + (w * 16 + cl) * 96 + ks * 32 + kg * 8);
#pragma unroll
        for (int ct = 0; ct < 8; ++ct) {
          f16x8 B = *(const f16x8*)(&hT[(ct * 16 + cl) * HSTR + ks * 32 + kg * 8]);
          acc[ct] = __builtin_amdgcn_mfma_f32_16x16x32_f16(A, B, acc[ct], 0, 0, 0);
        }
      }
#pragma unroll
      for (int ct = 0; ct < 8; ++ct) {
        f16x4 v;
#pragma unroll
        for (int i2 = 0; i2 < 4; ++i2) v[i2] = (_Float16)fmaxf(acc[ct][i2], 0.f);
        *(f16x4*)(&a1T[(ct * 16 + cl) * A1STR + w * 16 + kg * 4]) = v;
      }
    }
    __syncthreads();

    // ---- layer 2: K=64, O=128 (a2 aliases hT)
    {
      f32x4 acc[2][8];
#pragma unroll
      for (int r = 0; r < 2; ++r) {
        f32x4 bb = *(const f32x4*)(b2 + w * 32 + r * 16 + kg * 4);
#pragma unroll
        for (int ct = 0; ct < 8; ++ct) acc[r][ct] = bb;
      }
#pragma unroll
      for (int ks = 0; ks < 2; ++ks) {
        f16x8 A0 = *(const f16x8*)(W2f + (w * 32 + cl) * 64 + ks * 32 + kg * 8);
        f16x8 A1 = *(const f16x8*)(W2f + (w * 32 + 16 + cl) * 64 + ks * 32 + kg * 8);
#pragma unroll
        for (int ct = 0; ct < 8; ++ct) {
          f16x8 B = *(const f16x8*)(&a1T[(ct * 16 + cl) * A1STR + ks * 32 + kg * 8]);
          acc[0][ct] = __builtin_amdgcn_mfma_f32_16x16x32_f16(A0, B, acc[0][ct], 0, 0, 0);
          acc[1][ct] = __builtin_amdgcn_mfma_f32_16x16x32_f16(A1, B, acc[1][ct], 0, 0, 0);
        }
      }
#pragma unroll
      for (int r = 0; r < 2; ++r)
#pragma unroll
        for (int ct = 0; ct < 8; ++ct) {
          f16x4 v;
#pragma unroll
          for (int i2 = 0; i2 < 4; ++i2) v[i2] = (_Float16)fmaxf(acc[r][ct][i2], 0.f);
          *(f16x4*)(&hT[(ct * 16 + cl) * A2STR + w * 32 + r * 16 + kg * 4]) = v;
        }
    }
    __syncthreads();

    // ---- layer 3: K=128, O=256; fused maxpool
#pragma unroll
    for (int rh = 0; rh < 2; ++rh) {
      f32x4 acc[2][8];
#pragma unroll
      for (int r = 0; r < 2; ++r) {
        f32x4 bb = *(const f32x4*)(b3 + w * 64 + rh * 32 + r * 16 + kg * 4);
#pragma unroll
        for (int ct = 0; ct < 8; ++ct) acc[r][ct] = bb;
      }
#pragma unroll
      for (int ks = 0; ks < 4; ++ks) {
        f16x8 A0 = *(const f16x8*)(W3f + (w * 64 + rh * 32 + cl) * 128 + ks * 32 + kg * 8);
        f16x8 A1 = *(const f16x8*)(W3f + (w * 64 + rh * 32 + 16 + cl) * 128 + ks * 32 + kg * 8);
#pragma unroll
        for (int ct = 0; ct < 8; ++ct) {
          f16x8 B = *(const f16x8*)(&hT[(ct * 16 + cl) * A2STR + ks * 32 + kg * 8]);
          acc[0][ct] = __builtin_amdgcn_mfma_f32_16x16x32_f16(A0, B, acc[0][ct], 0, 0, 0);
          acc[1][ct] = __builtin_amdgcn_mfma_f32_16x16x32_f16(A1, B, acc[1][ct], 0, 0, 0);
        }
      }
#pragma unroll
      for (int r = 0; r < 2; ++r)
#pragma unroll
        for (int sl = 0; sl < 4; ++sl) {
          float vv[4];
#pragma unroll
          for (int i2 = 0; i2 < 4; ++i2) {
            float m0 = fmaxf(acc[r][sl * 2][i2], 0.f);
            float m1 = fmaxf(acc[r][sl * 2 + 1][i2], 0.f);
            float mv = fmaxf(m0, m1);
            mv = fmaxf(mv, __shfl_xor(mv, 1, 64));
            mv = fmaxf(mv, __shfl_xor(mv, 2, 64));
            mv = fmaxf(mv, __shfl_xor(mv, 4, 64));
            mv = fmaxf(mv, __shfl_xor(mv, 8, 64));
            vv[i2] = mv;
          }
          if (cl == 0) {
            int ob = w * 64 + rh * 32 + r * 16 + kg * 4;
#pragma unroll
            for (int i2 = 0; i2 < 4; ++i2)
              out2[((size_t)(b * 256 + ob + i2)) * NP + s0 + sl] = vv[i2];
          }
        }
    }
    __syncthreads();  // LDS + mitem reuse protection
  }
}

extern "C" void kernel_launch(void* const* d_in, const int* in_sizes, int n_in, void* d_out,
                              int out_size, void* d_ws, size_t ws_size, hipStream_t stream) {
  const float* xyz = (const float*)d_in[0];
  const float* feat = (const float*)d_in[1];
  const float* W1 = (const float*)d_in[2];
  const float* b1 = (const float*)d_in[3];
  const float* W2 = (const float*)d_in[4];
  const float* b2 = (const float*)d_in[5];
  const float* W3 = (const float*)d_in[6];
  const float* b3 = (const float*)d_in[7];
  float* out = (float*)d_out;
  char* ws = (char*)d_ws;
  float* xyzT = (float*)ws;                    // 512 KB
  _Float16* featF = (_Float16*)(ws + 524288);  // 4 MB
  _Float16* W1f = (_Float16*)(ws + 4718592);   // 12 KB
  _Float16* W2f = (_Float16*)(ws + 4730880);   // 16 KB
  _Float16* W3f = (_Float16*)(ws + 4747264);   // 64 KB
  unsigned* ctr = (unsigned*)(ws + 4812800);   // 18 x 64B counters

  hipLaunchKernelGGL(init_kernel, dim3(1), dim3(64), 0, stream, ctr);
  hipLaunchKernelGGL(fused_kernel, dim3(256), dim3(256), 0, stream, xyz, feat, W1, b1, W2, b2, W3,
                     b3, out, featF, xyzT, W1f, W2f, W3f, ctr);
}

// Round 11
// 338.232 us; speedup vs baseline: 1.6222x; 1.6222x over previous
//
#include <hip/hip_runtime.h>

#define NB 16
#define NN 2048
#define NP 512
#define NS 32
#define NC 64
#define NWORK 480

typedef _Float16 f16x8 __attribute__((ext_vector_type(8)));
typedef _Float16 f16x4 __attribute__((ext_vector_type(4)));
typedef float f32x4 __attribute__((ext_vector_type(4)));
typedef float f32x2 __attribute__((ext_vector_type(2)));

__device__ __forceinline__ float sqdist(float dx, float dy, float dz) {
  return __fadd_rn(__fadd_rn(__fmul_rn(dx, dx), __fmul_rn(dy, dy)), __fmul_rn(dz, dz));
}

__device__ __forceinline__ f32x2 pk_add(f32x2 a, f32x2 b) {
  f32x2 d;
  asm("v_pk_add_f32 %0, %1, %2" : "=v"(d) : "v"(a), "v"(b));
  return d;
}
__device__ __forceinline__ f32x2 pk_mul(f32x2 a, f32x2 b) {
  f32x2 d;
  asm("v_pk_mul_f32 %0, %1, %2" : "=v"(d) : "v"(a), "v"(b));
  return d;
}

template <int CTRL>
__device__ __forceinline__ float dppmaxf(float m) {
  int t = __builtin_amdgcn_update_dpp(0, __float_as_int(m), CTRL, 0xf, 0xf, true);
  return fmaxf(m, __int_as_float(t));  // 0-fill safe: all values >= 0
}

__device__ __forceinline__ unsigned ld_relax(const unsigned* p) {
  return __hip_atomic_load(p, __ATOMIC_RELAXED, __HIP_MEMORY_SCOPE_AGENT);
}
// bounded spin: relaxed polls + one final acquire (L1/L2 inv) once satisfied
__device__ __forceinline__ void waitge(const unsigned* p, unsigned need) {
  if (ld_relax(p) < need) {
    unsigned spins = 0;
    while (ld_relax(p) < need) {
      __builtin_amdgcn_s_sleep(8);
      if (++spins > (1u << 22)) break;  // safety valve — never expected
    }
  }
  (void)__hip_atomic_load(p, __ATOMIC_ACQUIRE, __HIP_MEMORY_SCOPE_AGENT);
}

__global__ void init_kernel(unsigned* ctr) {
  if (threadIdx.x < 18) ctr[threadIdx.x * 16] = 0;  // 64B-strided counters
}

#define HSTR 104   // hT stride in f16 (96 padded)
#define A1STR 72   // a1 stride (64 padded)
#define A2STR 136  // a2 stride (128 padded)
#define A1OFF 17408

// ---------------------------------------------------------------------------
// Fused persistent kernel, 512 blocks (2/CU). Proven r9 structure, one change:
// blocks 256..271 (the dispatch-order CU-mates of FPS blocks 0..15 under
// sequential round-robin placement) return immediately, so each FPS block gets
// a dedicated CU for its latency-critical serial loop.
//   blocks 0..15   : FPS producer, publishes progress every 64 iters
//   blocks 256..271: idle (placement heuristic — perf only, not correctness)
//   others (480)   : prep/wconv -> stage gate -> item queue: (b,sg) ball+MFMA
// ---------------------------------------------------------------------------
__global__ __launch_bounds__(256, 2) void fused_kernel(
    const float* __restrict__ xyz, const float* __restrict__ feat,
    const float* __restrict__ W1, const float* __restrict__ b1, const float* __restrict__ W2,
    const float* __restrict__ b2, const float* __restrict__ W3, const float* __restrict__ b3,
    float* __restrict__ out, _Float16* __restrict__ featF, float* __restrict__ xyzT,
    _Float16* __restrict__ W1f, _Float16* __restrict__ W2f, _Float16* __restrict__ W3f,
    unsigned* __restrict__ ctr) {
  __shared__ __align__(16) char sm[53824];
  __shared__ unsigned mitem;
  const int bid = blockIdx.x;
  const int t = threadIdx.x;
  float* newxyz = out;

  if (bid >= 256 && bid < 272) return;  // free the FPS CUs

  if (bid < NB) {
    // ================= FPS producer role =================
    const int b = bid;
    const int w = t >> 6;
    const float* X = xyz + (size_t)b * 3 * NN;
    float4* XL = (float4*)sm;           // 32768 B
    uint2* ck = (uint2*)(sm + 32768);   // 64 B

    f32x2 px[4], py[4], pz[4], dist[4];
#pragma unroll
    for (int jj = 0; jj < 4; ++jj) {
      int n0 = t + 256 * jj, n1 = n0 + 1024;
      px[jj] = f32x2{X[n0], X[n1]};
      py[jj] = f32x2{X[NN + n0], X[NN + n1]};
      pz[jj] = f32x2{X[2 * NN + n0], X[2 * NN + n1]};
      dist[jj] = f32x2{1e10f, 1e10f};
      XL[n0] = make_float4(px[jj].x, py[jj].x, pz[jj].x, 0.f);
      XL[n1] = make_float4(px[jj].y, py[jj].y, pz[jj].y, 0.f);
    }
    float cx = X[0], cy = X[NN], cz = X[2 * NN];
    __syncthreads();
    int buf = 0;
    for (int i = 0; i < NP; ++i) {
      if (t == 0) {
        // device-scope relaxed stores -> data reaches shared L3 (cross-XCD)
        __hip_atomic_store(&newxyz[b * 3 * NP + i], cx, __ATOMIC_RELAXED,
                           __HIP_MEMORY_SCOPE_AGENT);
        __hip_atomic_store(&newxyz[b * 3 * NP + NP + i], cy, __ATOMIC_RELAXED,
                           __HIP_MEMORY_SCOPE_AGENT);
        __hip_atomic_store(&newxyz[b * 3 * NP + 2 * NP + i], cz, __ATOMIC_RELAXED,
                           __HIP_MEMORY_SCOPE_AGENT);
        if ((i & 63) == 63)  // publish (release: belt-and-braces visibility)
          __hip_atomic_store(&ctr[b * 16], (unsigned)(i + 1), __ATOMIC_RELEASE,
                             __HIP_MEMORY_SCOPE_AGENT);
      }
      const f32x2 ncx = f32x2{-cx, -cx}, ncy = f32x2{-cy, -cy}, ncz = f32x2{-cz, -cz};
      float hm[4];
#pragma unroll
      for (int jj = 0; jj < 4; ++jj) {
        f32x2 dx = pk_add(px[jj], ncx);
        f32x2 dy = pk_add(py[jj], ncy);
        f32x2 dz = pk_add(pz[jj], ncz);
        f32x2 s = pk_add(pk_add(pk_mul(dx, dx), pk_mul(dy, dy)), pk_mul(dz, dz));
        f32x2 d = dist[jj];
        d.x = fminf(d.x, s.x);
        d.y = fminf(d.y, s.y);
        dist[jj] = d;
        hm[jj] = fmaxf(d.x, d.y);
      }
      float m = fmaxf(fmaxf(hm[0], hm[1]), fmaxf(hm[2], hm[3]));
      m = dppmaxf<0x111>(m);
      m = dppmaxf<0x112>(m);
      m = dppmaxf<0x114>(m);
      m = dppmaxf<0x118>(m);
      m = dppmaxf<0x142>(m);
      m = dppmaxf<0x143>(m);
      const float vmax = __int_as_float(__builtin_amdgcn_readlane(__float_as_int(m), 63));
      unsigned long long mm[8];
#pragma unroll
      for (int jj = 0; jj < 4; ++jj) {
        mm[jj] = __ballot(dist[jj].x == vmax);
        mm[4 + jj] = __ballot(dist[jj].y == vmax);
      }
      unsigned nw = 0;
#pragma unroll
      for (int q = 7; q >= 0; --q)
        if (mm[q]) nw = 256u * (unsigned)q + (unsigned)(w << 6) + (unsigned)__builtin_ctzll(mm[q]);
      if ((t & 63) == 0) ck[buf * 4 + w] = make_uint2(__float_as_uint(vmax), nw);
      __syncthreads();
      uint4 c01 = *(const uint4*)&ck[buf * 4 + 0];
      uint4 c23 = *(const uint4*)&ck[buf * 4 + 2];
      unsigned v = c01.x, n = c01.y;
      if (c01.z > v || (c01.z == v && c01.w < n)) { v = c01.z; n = c01.w; }
      if (c23.x > v || (c23.x == v && c23.y < n)) { v = c23.x; n = c23.y; }
      if (c23.z > v || (c23.z == v && c23.w < n)) { v = c23.z; n = c23.w; }
      float4 c = XL[n];
      cx = c.x;
      cy = c.y;
      cz = c.z;
      buf ^= 1;
    }
  } else {
    // ================= worker role: prep + wconv, then stage release =======
    const int wid = (bid < 256) ? (bid - NB) : (bid - 32);
    for (int rep = 0; rep < 2; ++rep) {
      int p = wid + rep * NWORK;
      if (p >= 512) break;
      float(*tile)[65] = (float(*)[65])sm;
      const int b = p >> 5;
      const int n0 = (p & 31) * 64;
      const int g = t >> 6, l = t & 63;
      if (g == 0) {
        int n = n0 + l;
        float4 q;
        q.x = xyz[(size_t)b * 3 * NN + n];
        q.y = xyz[(size_t)b * 3 * NN + NN + n];
        q.z = xyz[(size_t)b * 3 * NN + 2 * NN + n];
        q.w = 0.f;
        ((float4*)xyzT)[(size_t)b * NN + n] = q;
      }
      __syncthreads();  // tile reuse across reps
#pragma unroll
      for (int r = 0; r < 16; ++r) {
        int c = g * 16 + r;
        tile[c][l] = feat[((size_t)b * NC + c) * NN + n0 + l];
      }
      __syncthreads();
#pragma unroll
      for (int r = 0; r < 16; ++r) {
        int nl = g * 16 + r;
        featF[((size_t)(b * NN + n0 + nl)) * NC + l] = (_Float16)tile[l][nl];
      }
    }
    if (wid == 31) {
      for (int i = t; i < 256 * 128; i += 256) {
        if (i < 64 * 96) {
          int o = i / 96, k = i - o * 96;
          float v = (k < 64) ? W1[o * 67 + 3 + k] : ((k < 67) ? W1[o * 67 + (k - 64)] : 0.f);
          W1f[i] = (_Float16)v;
        }
        if (i < 128 * 64) W2f[i] = (_Float16)W2[i];
        W3f[i] = (_Float16)W3[i];
      }
    }
    __syncthreads();  // all waves' stores drained (vmcnt before barrier)
    if (t == 0)
      (void)__hip_atomic_fetch_add(&ctr[16 * 16], 1u, __ATOMIC_RELEASE,
                                   __HIP_MEMORY_SCOPE_AGENT);
  }

  // ================= stage gate, then item queue =================
  if (t == 0) waitge(&ctr[16 * 16], NWORK);
  __syncthreads();

  _Float16* hT = (_Float16*)sm;
  _Float16* a1T = (_Float16*)(sm) + A1OFF;
  int(*idx_l)[32] = (int(*)[32])(sm + 53248);
  float(*cxyz)[4] = (float(*)[4])(sm + 53760);
  const int lane = t & 63, w = t >> 6;
  const int cl = lane & 15;
  const int kg = lane >> 4;
  float* out2 = out + NB * 3 * NP;

  for (;;) {
    if (t == 0)
      mitem = __hip_atomic_fetch_add(&ctr[17 * 16], 1u, __ATOMIC_RELAXED,
                                     __HIP_MEMORY_SCOPE_AGENT);
    __syncthreads();
    const unsigned m = mitem;
    if (m >= (unsigned)(NB * 128)) break;
    const int b = (int)(m & 15u);
    const int sg = (int)(m >> 4);
    const int s0 = sg * 4;
    if (t == 0) waitge(&ctr[b * 16], (unsigned)(s0 + 4));
    __syncthreads();

    // ---- phase 0: ball query, one wave per s (bit-exact ballot scan)
    {
      const float* X = xyz + (size_t)b * 3 * NN;
      const int sW = s0 + w;
      const float cxw = newxyz[b * 3 * NP + sW];
      const float cyw = newxyz[b * 3 * NP + NP + sW];
      const float czw = newxyz[b * 3 * NP + 2 * NP + sW];
      if (lane == 0) {
        cxyz[w][0] = cxw;
        cxyz[w][1] = cyw;
        cxyz[w][2] = czw;
      }
      const float r2 = (float)(0.2 * 0.2);
      int total = 0, first = 0;
      bool havefirst = false;
      for (int c0 = 0; c0 < NN; c0 += 64) {
        int n = c0 + lane;
        float d2 = sqdist(X[n] - cxw, X[NN + n] - cyw, X[2 * NN + n] - czw);
        bool hit = d2 < r2;
        unsigned long long mask = __ballot(hit);
        if (!havefirst && mask) {
          first = c0 + __builtin_ctzll(mask);
          havefirst = true;
        }
        if (hit) {
          int pos = total + (int)__popcll(mask & ((1ull << lane) - 1ull));
          if (pos < NS) idx_l[w][pos] = n;
        }
        total += (int)__popcll(mask);
        if (total >= NS) break;
      }
      if (total < NS && lane >= total && lane < NS) idx_l[w][lane] = first;
    }
    __syncthreads();

    // ---- phase 1: gather hT[128 cols][96 k]
    {
      const int col = t & 127, hf = t >> 7;
      const int n = idx_l[col >> 5][col & 31];
      const _Float16* F = featF + (size_t)(b * NN + n) * NC;
#pragma unroll
      for (int j = 0; j < 4; ++j) {
        int p = hf * 4 + j;
        *(f16x8*)(&hT[col * HSTR + p * 8]) = *(const f16x8*)(F + p * 8);
      }
      if (hf == 0) {
        float4 pnt = ((const float4*)xyzT)[(size_t)b * NN + n];
        f16x8 v = {};
        v[0] = (_Float16)(pnt.x - cxyz[col >> 5][0]);
        v[1] = (_Float16)(pnt.y - cxyz[col >> 5][1]);
        v[2] = (_Float16)(pnt.z - cxyz[col >> 5][2]);
        *(f16x8*)(&hT[col * HSTR + 64]) = v;
      } else {
        f16x8 z = {};
        *(f16x8*)(&hT[col * HSTR + 72]) = z;
        *(f16x8*)(&hT[col * HSTR + 80]) = z;
        *(f16x8*)(&hT[col * HSTR + 88]) = z;
      }
    }
    __syncthreads();

    // ---- layer 1: K=96, O=64
    {
      f32x4 acc[8];
      {
        f32x4 bb = *(const f32x4*)(b1 + w * 16 + kg * 4);
#pragma unroll
        for (int ct = 0; ct < 8; ++ct) acc[ct] = bb;
      }
#pragma unroll
      for (int ks = 0; ks < 3; ++ks) {
        f16x8 A = *(const f16x8*)(W1f + (w * 16 + cl) * 96 + ks * 32 + kg * 8);
#pragma unroll
        for (int ct = 0; ct < 8; ++ct) {
          f16x8 B = *(const f16x8*)(&hT[(ct * 16 + cl) * HSTR + ks * 32 + kg * 8]);
          acc[ct] = __builtin_amdgcn_mfma_f32_16x16x32_f16(A, B, acc[ct], 0, 0, 0);
        }
      }
#pragma unroll
      for (int ct = 0; ct < 8; ++ct) {
        f16x4 v;
#pragma unroll
        for (int i2 = 0; i2 < 4; ++i2) v[i2] = (_Float16)fmaxf(acc[ct][i2], 0.f);
        *(f16x4*)(&a1T[(ct * 16 + cl) * A1STR + w * 16 + kg * 4]) = v;
      }
    }
    __syncthreads();

    // ---- layer 2: K=64, O=128 (a2 aliases hT)
    {
      f32x4 acc[2][8];
#pragma unroll
      for (int r = 0; r < 2; ++r) {
        f32x4 bb = *(const f32x4*)(b2 + w * 32 + r * 16 + kg * 4);
#pragma unroll
        for (int ct = 0; ct < 8; ++ct) acc[r][ct] = bb;
      }
#pragma unroll
      for (int ks = 0; ks < 2; ++ks) {
        f16x8 A0 = *(const f16x8*)(W2f + (w * 32 + cl) * 64 + ks * 32 + kg * 8);
        f16x8 A1 = *(const f16x8*)(W2f + (w * 32 + 16 + cl) * 64 + ks * 32 + kg * 8);
#pragma unroll
        for (int ct = 0; ct < 8; ++ct) {
          f16x8 B = *(const f16x8*)(&a1T[(ct * 16 + cl) * A1STR + ks * 32 + kg * 8]);
          acc[0][ct] = __builtin_amdgcn_mfma_f32_16x16x32_f16(A0, B, acc[0][ct], 0, 0, 0);
          acc[1][ct] = __builtin_amdgcn_mfma_f32_16x16x32_f16(A1, B, acc[1][ct], 0, 0, 0);
        }
      }
#pragma unroll
      for (int r = 0; r < 2; ++r)
#pragma unroll
        for (int ct = 0; ct < 8; ++ct) {
          f16x4 v;
#pragma unroll
          for (int i2 = 0; i2 < 4; ++i2) v[i2] = (_Float16)fmaxf(acc[r][ct][i2], 0.f);
          *(f16x4*)(&hT[(ct * 16 + cl) * A2STR + w * 32 + r * 16 + kg * 4]) = v;
        }
    }
    __syncthreads();

    // ---- layer 3: K=128, O=256; fused maxpool
#pragma unroll
    for (int rh = 0; rh < 2; ++rh) {
      f32x4 acc[2][8];
#pragma unroll
      for (int r = 0; r < 2; ++r) {
        f32x4 bb = *(const f32x4*)(b3 + w * 64 + rh * 32 + r * 16 + kg * 4);
#pragma unroll
        for (int ct = 0; ct < 8; ++ct) acc[r][ct] = bb;
      }
#pragma unroll
      for (int ks = 0; ks < 4; ++ks) {
        f16x8 A0 = *(const f16x8*)(W3f + (w * 64 + rh * 32 + cl) * 128 + ks * 32 + kg * 8);
        f16x8 A1 = *(const f16x8*)(W3f + (w * 64 + rh * 32 + 16 + cl) * 128 + ks * 32 + kg * 8);
#pragma unroll
        for (int ct = 0; ct < 8; ++ct) {
          f16x8 B = *(const f16x8*)(&hT[(ct * 16 + cl) * A2STR + ks * 32 + kg * 8]);
          acc[0][ct] = __builtin_amdgcn_mfma_f32_16x16x32_f16(A0, B, acc[0][ct], 0, 0, 0);
          acc[1][ct] = __builtin_amdgcn_mfma_f32_16x16x32_f16(A1, B, acc[1][ct], 0, 0, 0);
        }
      }
#pragma unroll
      for (int r = 0; r < 2; ++r)
#pragma unroll
        for (int sl = 0; sl < 4; ++sl) {
          float vv[4];
#pragma unroll
          for (int i2 = 0; i2 < 4; ++i2) {
            float m0 = fmaxf(acc[r][sl * 2][i2], 0.f);
            float m1 = fmaxf(acc[r][sl * 2 + 1][i2], 0.f);
            float mv = fmaxf(m0, m1);
            mv = fmaxf(mv, __shfl_xor(mv, 1, 64));
            mv = fmaxf(mv, __shfl_xor(mv, 2, 64));
            mv = fmaxf(mv, __shfl_xor(mv, 4, 64));
            mv = fmaxf(mv, __shfl_xor(mv, 8, 64));
            vv[i2] = mv;
          }
          if (cl == 0) {
            int ob = w * 64 + rh * 32 + r * 16 + kg * 4;
#pragma unroll
            for (int i2 = 0; i2 < 4; ++i2)
              out2[((size_t)(b * 256 + ob + i2)) * NP + s0 + sl] = vv[i2];
          }
        }
    }
    __syncthreads();  // LDS + mitem reuse protection
  }
}

extern "C" void kernel_launch(void* const* d_in, const int* in_sizes, int n_in, void* d_out,
                              int out_size, void* d_ws, size_t ws_size, hipStream_t stream) {
  const float* xyz = (const float*)d_in[0];
  const float* feat = (const float*)d_in[1];
  const float* W1 = (const float*)d_in[2];
  const float* b1 = (const float*)d_in[3];
  const float* W2 = (const float*)d_in[4];
  const float* b2 = (const float*)d_in[5];
  const float* W3 = (const float*)d_in[6];
  const float* b3 = (const float*)d_in[7];
  float* out = (float*)d_out;
  char* ws = (char*)d_ws;
  float* xyzT = (float*)ws;                    // 512 KB
  _Float16* featF = (_Float16*)(ws + 524288);  // 4 MB
  _Float16* W1f = (_Float16*)(ws + 4718592);   // 12 KB
  _Float16* W2f = (_Float16*)(ws + 4730880);   // 16 KB
  _Float16* W3f = (_Float16*)(ws + 4747264);   // 64 KB
  unsigned* ctr = (unsigned*)(ws + 4812800);   // 18 x 64B counters

  hipLaunchKernelGGL(init_kernel, dim3(1), dim3(64), 0, stream, ctr);
  hipLaunchKernelGGL(fused_kernel, dim3(512), dim3(256), 0, stream, xyz, feat, W1, b1, W2, b2, W3,
                     b3, out, featF, xyzT, W1f, W2f, W3f, ctr);
}